// Round 1
// baseline (424.577 us; speedup 1.0000x reference)
//
#include <hip/hip_runtime.h>
#include <hip/hip_bf16.h>
#include <math.h>

#define BB 16
#define NN 512
#define DD 256
#define KK 12

typedef __bf16 bf16x8 __attribute__((ext_vector_type(8)));
typedef __bf16 bf16x4 __attribute__((ext_vector_type(4)));
typedef float  f32x4  __attribute__((ext_vector_type(4)));

// workspace layout (bytes)
#define WS_WM     0              // wm[b,n] = w*mask_n, f32, 32KB
#define WS_S      32768          // s[b,m]  = mask_m/neigh, f32, 32KB
#define WS_NODEBF 65536          // node bf16 [B][N][D], 4MB
#define WS_NODET  4259840        // node bf16 transposed [B][D][N], 4MB
#define WS_WKBF   8454144        // Wk bf16 [K][D][D], 1.5MB
#define WS_WSBF   10027008       // Ws bf16 [D][D], 128KB
#define WS_T      10158080       // T bf16 [K][B][N][D], 50MB
// total ~60.5 MB

// ---------------------------------------------------------------- k1: w, all_weight, wm, node_bf16
__global__ __launch_bounds__(256) void k1_prep(const float* __restrict__ node,
        const float* __restrict__ Ww, const float* __restrict__ bw,
        const int* __restrict__ node_mask,
        float* __restrict__ wm, __bf16* __restrict__ node_bf,
        float* __restrict__ all_w) {
    int t = threadIdx.x;
    int lane = t & 63;
    int row = blockIdx.x * 4 + (t >> 6);           // b*N + n
    const float4 nv = *(const float4*)(node + (size_t)row * DD + lane * 4);
    const float4 wv = *(const float4*)(Ww + lane * 4);
    float dot = nv.x*wv.x + nv.y*wv.y + nv.z*wv.z + nv.w*wv.w;
    #pragma unroll
    for (int off = 32; off > 0; off >>= 1) dot += __shfl_xor(dot, off);
    float w = 1.0f / (1.0f + expf(-(dot + bw[0])));
    int mk = node_mask[row];
    if (lane == 0) {
        wm[row]    = w * (float)mk;
        all_w[row] = w;
    }
    bf16x4 nb = {(__bf16)nv.x, (__bf16)nv.y, (__bf16)nv.z, (__bf16)nv.w};
    *(bf16x4*)(node_bf + (size_t)row * DD + lane * 4) = nb;
}

// ---------------------------------------------------------------- k1b: Wk, Ws -> bf16
__global__ __launch_bounds__(256) void k1b_convert(const float* __restrict__ Wk,
        const float* __restrict__ Ws, __bf16* __restrict__ Wk_bf, __bf16* __restrict__ Ws_bf) {
    const int KDD = KK * DD * DD;
    int idx = (blockIdx.x * 256 + threadIdx.x) * 4;
    if (idx < KDD) {
        float4 v = *(const float4*)(Wk + idx);
        bf16x4 o = {(__bf16)v.x, (__bf16)v.y, (__bf16)v.z, (__bf16)v.w};
        *(bf16x4*)(Wk_bf + idx) = o;
    } else {
        int j = idx - KDD;
        if (j < DD * DD) {
            float4 v = *(const float4*)(Ws + j);
            bf16x4 o = {(__bf16)v.x, (__bf16)v.y, (__bf16)v.z, (__bf16)v.w};
            *(bf16x4*)(Ws_bf + j) = o;
        }
    }
}

// ---------------------------------------------------------------- k2: node_bf [B][N][D] -> node_t [B][D][N]
__global__ __launch_bounds__(256) void k2_transpose(const __bf16* __restrict__ src,
                                                    __bf16* __restrict__ dst) {
    __shared__ __bf16 tile[64][65];
    int bx = blockIdx.x;
    int b = bx >> 5; int rest = bx & 31; int nt = rest >> 2; int dt = rest & 3;
    int n0 = nt * 64, d0 = dt * 64;
    int t = threadIdx.x;
    #pragma unroll
    for (int i = 0; i < 16; i++) {
        int idx = i * 256 + t;
        int n = idx >> 6, d = idx & 63;
        tile[n][d] = src[((size_t)(b * NN + n0 + n)) * DD + d0 + d];
    }
    __syncthreads();
    #pragma unroll
    for (int i = 0; i < 16; i++) {
        int idx = i * 256 + t;
        int d = idx >> 6, n = idx & 63;
        dst[((size_t)(b * DD + d0 + d)) * NN + n0 + n] = tile[n][d];
    }
}

// ---------------------------------------------------------------- k3: s[b,m] = mask_m / max(1, sum_{k,j} g)
__global__ __launch_bounds__(256) void k3_neigh(const int* __restrict__ graphs,
        const int* __restrict__ node_mask, float* __restrict__ s) {
    int bx = blockIdx.x;
    int b = bx >> 9, m = bx & 511;
    int t = threadIdx.x;
    int j0 = t, j1 = t + 256;
    int mk0 = (j0 != m) ? node_mask[b * NN + j0] : 0;
    int mk1 = (j1 != m) ? node_mask[b * NN + j1] : 0;
    int sum = 0;
    #pragma unroll
    for (int k = 0; k < KK; k++) {
        const int* g = graphs + ((size_t)((k * BB + b) * NN + m)) * NN;
        sum += mk0 * g[j0] + mk1 * g[j1];
    }
    #pragma unroll
    for (int off = 32; off > 0; off >>= 1) sum += __shfl_xor(sum, off);
    __shared__ int partial[4];
    if ((t & 63) == 0) partial[t >> 6] = sum;
    __syncthreads();
    if (t == 0) {
        int tot = partial[0] + partial[1] + partial[2] + partial[3];
        int mm = node_mask[b * NN + m];
        tot *= mm;
        float fn = (float)(tot >= 1 ? tot : 1);
        s[bx] = (float)mm / fn;
    }
}

// ---------------------------------------------------------------- k4: T[k,b,m,e] = sum_n A(g,wm)[m,n] * node[b,n,e]
__global__ __launch_bounds__(256) void k4_stageA(const int* __restrict__ graphs,
        const float* __restrict__ wm, const __bf16* __restrict__ node_t,
        __bf16* __restrict__ T) {
    __shared__ __align__(16) __bf16 Asub[64][72];
    __shared__ __align__(16) __bf16 Bsub[256][72];
    int bx = blockIdx.x;
    int mt = bx & 7;
    int kb = bx >> 3;
    int b = kb & 15;
    int k = kb >> 4;
    int m0 = mt * 64;
    int t = threadIdx.x;
    int lane = t & 63;
    int wave = t >> 6;                 // wave -> d block of 64
    int q = lane >> 4;
    int l16 = lane & 15;

    f32x4 acc[4][4];
    #pragma unroll
    for (int i = 0; i < 4; i++)
        #pragma unroll
        for (int j = 0; j < 4; j++) acc[i][j] = (f32x4){0.f, 0.f, 0.f, 0.f};

    int am = t >> 2;                   // A row 0..63
    int aq = t & 3;
    const int* grow = graphs + ((size_t)((k * BB + b) * NN + m0 + am)) * NN;
    int mg = m0 + am;                  // global row index (for diagonal)
    int bd = t >> 2;                   // B tile d row base
    int bq = t & 3;

    for (int n0 = 0; n0 < NN; n0 += 64) {
        // A tile: masked, w-scaled adjacency -> bf16
        #pragma unroll
        for (int i = 0; i < 4; i++) {
            int nbase = n0 + aq * 16 + i * 4;
            int4 g = *(const int4*)(grow + nbase);
            float4 w4 = *(const float4*)(wm + b * NN + nbase);
            __bf16 v0 = (__bf16)((nbase + 0 != mg) ? (float)g.x * w4.x : 0.0f);
            __bf16 v1 = (__bf16)((nbase + 1 != mg) ? (float)g.y * w4.y : 0.0f);
            __bf16 v2 = (__bf16)((nbase + 2 != mg) ? (float)g.z * w4.z : 0.0f);
            __bf16 v3 = (__bf16)((nbase + 3 != mg) ? (float)g.w * w4.w : 0.0f);
            bf16x4 pack = {v0, v1, v2, v3};
            *(bf16x4*)&Asub[am][aq * 16 + i * 4] = pack;
        }
        // B tile: node_t[b][d][n0..n0+63] (already [d][n] so b-frags read contiguous n)
        #pragma unroll
        for (int p = 0; p < 4; p++) {
            int d = bd + p * 64;
            const __bf16* src = node_t + ((size_t)(b * DD + d)) * NN + n0 + bq * 16;
            bf16x8 u0 = *(const bf16x8*)(src);
            bf16x8 u1 = *(const bf16x8*)(src + 8);
            *(bf16x8*)&Bsub[d][bq * 16]     = u0;
            *(bf16x8*)&Bsub[d][bq * 16 + 8] = u1;
        }
        __syncthreads();
        bf16x8 af[4][2], bfr[4][2];
        #pragma unroll
        for (int fm = 0; fm < 4; fm++)
            #pragma unroll
            for (int kk = 0; kk < 2; kk++)
                af[fm][kk] = *(const bf16x8*)&Asub[fm * 16 + l16][kk * 32 + q * 8];
        #pragma unroll
        for (int fd = 0; fd < 4; fd++)
            #pragma unroll
            for (int kk = 0; kk < 2; kk++)
                bfr[fd][kk] = *(const bf16x8*)&Bsub[wave * 64 + fd * 16 + l16][kk * 32 + q * 8];
        #pragma unroll
        for (int fm = 0; fm < 4; fm++)
            #pragma unroll
            for (int fd = 0; fd < 4; fd++)
                #pragma unroll
                for (int kk = 0; kk < 2; kk++)
                    acc[fm][fd] = __builtin_amdgcn_mfma_f32_16x16x32_bf16(
                        af[fm][kk], bfr[fd][kk], acc[fm][fd], 0, 0, 0);
        __syncthreads();
    }
    // epilogue: store T bf16. C/D layout: col=lane&15, row=(lane>>4)*4+reg (m89/m91)
    #pragma unroll
    for (int fm = 0; fm < 4; fm++)
        #pragma unroll
        for (int fd = 0; fd < 4; fd++) {
            int col = wave * 64 + fd * 16 + l16;
            #pragma unroll
            for (int r = 0; r < 4; r++) {
                int m = m0 + fm * 16 + q * 4 + r;
                T[((size_t)((k * BB + b) * NN + m)) * DD + col] = (__bf16)acc[fm][fd][r];
            }
        }
}

// ---------------------------------------------------------------- k5: out = relu(s*agg + self + bs)
__global__ __launch_bounds__(256) void k5_stageB(const __bf16* __restrict__ T,
        const __bf16* __restrict__ Wk_bf, const __bf16* __restrict__ node_bf,
        const __bf16* __restrict__ Ws_bf, const float* __restrict__ bs,
        const float* __restrict__ s, float* __restrict__ out) {
    __shared__ __align__(16) __bf16 AT[32][72];
    __shared__ __align__(16) __bf16 BW[256][72];
    int bx = blockIdx.x;
    int b = bx >> 4;
    int m0 = (bx & 15) * 32;
    int t = threadIdx.x;
    int lane = t & 63;
    int wave = t >> 6;
    int q = lane >> 4;
    int l16 = lane & 15;

    f32x4 acc[2][4];
    #pragma unroll
    for (int i = 0; i < 2; i++)
        #pragma unroll
        for (int j = 0; j < 4; j++) acc[i][j] = (f32x4){0.f, 0.f, 0.f, 0.f};

    int atm = t >> 3; int atc = (t & 7) * 8;
    int bwd = t >> 2; int bwc = (t & 3) * 16;

    for (int k = 0; k < KK; k++) {
        for (int et = 0; et < 4; et++) {
            int e0 = et * 64;
            *(bf16x8*)&AT[atm][atc] =
                *(const bf16x8*)(T + ((size_t)((k * BB + b) * NN + m0 + atm)) * DD + e0 + atc);
            #pragma unroll
            for (int p = 0; p < 4; p++) {
                int d = bwd + p * 64;
                const __bf16* srcp = Wk_bf + ((size_t)(k * DD + d)) * DD + e0 + bwc;
                *(bf16x8*)&BW[d][bwc]     = *(const bf16x8*)(srcp);
                *(bf16x8*)&BW[d][bwc + 8] = *(const bf16x8*)(srcp + 8);
            }
            __syncthreads();
            bf16x8 af[2][2], bfr[4][2];
            #pragma unroll
            for (int fm = 0; fm < 2; fm++)
                #pragma unroll
                for (int kk = 0; kk < 2; kk++)
                    af[fm][kk] = *(const bf16x8*)&AT[fm * 16 + l16][kk * 32 + q * 8];
            #pragma unroll
            for (int fd = 0; fd < 4; fd++)
                #pragma unroll
                for (int kk = 0; kk < 2; kk++)
                    bfr[fd][kk] = *(const bf16x8*)&BW[wave * 64 + fd * 16 + l16][kk * 32 + q * 8];
            #pragma unroll
            for (int fm = 0; fm < 2; fm++)
                #pragma unroll
                for (int fd = 0; fd < 4; fd++)
                    #pragma unroll
                    for (int kk = 0; kk < 2; kk++)
                        acc[fm][fd] = __builtin_amdgcn_mfma_f32_16x16x32_bf16(
                            af[fm][kk], bfr[fd][kk], acc[fm][fd], 0, 0, 0);
            __syncthreads();
        }
    }
    // scale aggregate part by s[b,m] = mask_m/neigh (self_info must stay unscaled)
    #pragma unroll
    for (int fm = 0; fm < 2; fm++) {
        float sv[4];
        #pragma unroll
        for (int r = 0; r < 4; r++) sv[r] = s[b * NN + m0 + fm * 16 + q * 4 + r];
        #pragma unroll
        for (int fd = 0; fd < 4; fd++)
            #pragma unroll
            for (int r = 0; r < 4; r++) acc[fm][fd][r] *= sv[r];
    }
    // self segment: + node @ Ws^T
    for (int et = 0; et < 4; et++) {
        int e0 = et * 64;
        *(bf16x8*)&AT[atm][atc] =
            *(const bf16x8*)(node_bf + ((size_t)(b * NN + m0 + atm)) * DD + e0 + atc);
        #pragma unroll
        for (int p = 0; p < 4; p++) {
            int d = bwd + p * 64;
            const __bf16* srcp = Ws_bf + (size_t)d * DD + e0 + bwc;
            *(bf16x8*)&BW[d][bwc]     = *(const bf16x8*)(srcp);
            *(bf16x8*)&BW[d][bwc + 8] = *(const bf16x8*)(srcp + 8);
        }
        __syncthreads();
        bf16x8 af[2][2], bfr[4][2];
        #pragma unroll
        for (int fm = 0; fm < 2; fm++)
            #pragma unroll
            for (int kk = 0; kk < 2; kk++)
                af[fm][kk] = *(const bf16x8*)&AT[fm * 16 + l16][kk * 32 + q * 8];
        #pragma unroll
        for (int fd = 0; fd < 4; fd++)
            #pragma unroll
            for (int kk = 0; kk < 2; kk++)
                bfr[fd][kk] = *(const bf16x8*)&BW[wave * 64 + fd * 16 + l16][kk * 32 + q * 8];
        #pragma unroll
        for (int fm = 0; fm < 2; fm++)
            #pragma unroll
            for (int fd = 0; fd < 4; fd++)
                #pragma unroll
                for (int kk = 0; kk < 2; kk++)
                    acc[fm][fd] = __builtin_amdgcn_mfma_f32_16x16x32_bf16(
                        af[fm][kk], bfr[fd][kk], acc[fm][fd], 0, 0, 0);
        __syncthreads();
    }
    // epilogue: + bs, relu, store f32
    #pragma unroll
    for (int fm = 0; fm < 2; fm++)
        #pragma unroll
        for (int fd = 0; fd < 4; fd++) {
            int col = wave * 64 + fd * 16 + l16;
            float bsv = bs[col];
            #pragma unroll
            for (int r = 0; r < 4; r++) {
                int m = m0 + fm * 16 + q * 4 + r;
                float v = acc[fm][fd][r] + bsv;
                out[((size_t)(b * NN + m)) * DD + col] = fmaxf(v, 0.0f);
            }
        }
}

// ----------------------------------------------------------------
extern "C" void kernel_launch(void* const* d_in, const int* in_sizes, int n_in,
                              void* d_out, int out_size, void* d_ws, size_t ws_size,
                              hipStream_t stream) {
    const float* node      = (const float*)d_in[0];
    const float* Ww        = (const float*)d_in[1];
    const float* bw        = (const float*)d_in[2];
    const float* Ws        = (const float*)d_in[3];
    const float* bs        = (const float*)d_in[4];
    const float* Wk        = (const float*)d_in[5];
    const int*   node_mask = (const int*)d_in[6];
    const int*   graphs    = (const int*)d_in[7];
    float* out   = (float*)d_out;
    float* all_w = out + (size_t)BB * NN * DD;

    char* ws = (char*)d_ws;
    float*  wm      = (float*)(ws + WS_WM);
    float*  sbuf    = (float*)(ws + WS_S);
    __bf16* node_bf = (__bf16*)(ws + WS_NODEBF);
    __bf16* node_t  = (__bf16*)(ws + WS_NODET);
    __bf16* Wk_bf   = (__bf16*)(ws + WS_WKBF);
    __bf16* Ws_bf   = (__bf16*)(ws + WS_WSBF);
    __bf16* Tbuf    = (__bf16*)(ws + WS_T);

    k1_prep    <<<2048, 256, 0, stream>>>(node, Ww, bw, node_mask, wm, node_bf, all_w);
    k1b_convert<<< 832, 256, 0, stream>>>(Wk, Ws, Wk_bf, Ws_bf);
    k2_transpose<<<512, 256, 0, stream>>>(node_bf, node_t);
    k3_neigh   <<<8192, 256, 0, stream>>>(graphs, node_mask, sbuf);
    k4_stageA  <<<1536, 256, 0, stream>>>(graphs, wm, node_t, Tbuf);
    k5_stageB  <<< 256, 256, 0, stream>>>(Tbuf, Wk_bf, node_bf, Ws_bf, bs, sbuf, out);
}

// Round 2
// 380.862 us; speedup vs baseline: 1.1148x; 1.1148x over previous
//
#include <hip/hip_runtime.h>
#include <hip/hip_bf16.h>
#include <math.h>

#define BB 16
#define NN 512
#define DD 256
#define KK 12

typedef __bf16 bf16x8 __attribute__((ext_vector_type(8)));
typedef __bf16 bf16x4 __attribute__((ext_vector_type(4)));
typedef float  f32x4  __attribute__((ext_vector_type(4)));

// workspace layout (bytes)
#define WS_WM     0              // wm[b,n] = w*mask_n, f32, 32KB
#define WS_NCNT   32768          // ncnt[b,m] int32 neighbor counts (atomic), 32KB
#define WS_NODEBF 65536          // node bf16 [B][N][D], 4MB
#define WS_NODET  4259840        // node bf16 transposed [B][D][N], 4MB
#define WS_WKBF   8454144        // Wk bf16 [K][D][D], 1.5MB
#define WS_WSBF   10027008       // Ws bf16 [D][D], 128KB
#define WS_T      10158080       // T bf16 [B][N][K][D]  (b,m,k,e), 50MB
// total ~60.5 MB

// ---------------------------------------------------------------- k1: w, all_weight, wm, node_bf16
__global__ __launch_bounds__(256) void k1_prep(const float* __restrict__ node,
        const float* __restrict__ Ww, const float* __restrict__ bw,
        const int* __restrict__ node_mask,
        float* __restrict__ wm, __bf16* __restrict__ node_bf,
        float* __restrict__ all_w) {
    int t = threadIdx.x;
    int lane = t & 63;
    int row = blockIdx.x * 4 + (t >> 6);           // b*N + n
    const float4 nv = *(const float4*)(node + (size_t)row * DD + lane * 4);
    const float4 wv = *(const float4*)(Ww + lane * 4);
    float dot = nv.x*wv.x + nv.y*wv.y + nv.z*wv.z + nv.w*wv.w;
    #pragma unroll
    for (int off = 32; off > 0; off >>= 1) dot += __shfl_xor(dot, off);
    float w = 1.0f / (1.0f + expf(-(dot + bw[0])));
    int mk = node_mask[row];
    if (lane == 0) {
        wm[row]    = w * (float)mk;
        all_w[row] = w;
    }
    bf16x4 nb = {(__bf16)nv.x, (__bf16)nv.y, (__bf16)nv.z, (__bf16)nv.w};
    *(bf16x4*)(node_bf + (size_t)row * DD + lane * 4) = nb;
}

// ---------------------------------------------------------------- k1b: Wk, Ws -> bf16
__global__ __launch_bounds__(256) void k1b_convert(const float* __restrict__ Wk,
        const float* __restrict__ Ws, __bf16* __restrict__ Wk_bf, __bf16* __restrict__ Ws_bf) {
    const int KDD = KK * DD * DD;
    int idx = (blockIdx.x * 256 + threadIdx.x) * 4;
    if (idx < KDD) {
        float4 v = *(const float4*)(Wk + idx);
        bf16x4 o = {(__bf16)v.x, (__bf16)v.y, (__bf16)v.z, (__bf16)v.w};
        *(bf16x4*)(Wk_bf + idx) = o;
    } else {
        int j = idx - KDD;
        if (j < DD * DD) {
            float4 v = *(const float4*)(Ws + j);
            bf16x4 o = {(__bf16)v.x, (__bf16)v.y, (__bf16)v.z, (__bf16)v.w};
            *(bf16x4*)(Ws_bf + j) = o;
        }
    }
}

// ---------------------------------------------------------------- k2: node_bf [B][N][D] -> node_t [B][D][N]
__global__ __launch_bounds__(256) void k2_transpose(const __bf16* __restrict__ src,
                                                    __bf16* __restrict__ dst) {
    __shared__ __bf16 tile[64][65];
    int bx = blockIdx.x;
    int b = bx >> 5; int rest = bx & 31; int nt = rest >> 2; int dt = rest & 3;
    int n0 = nt * 64, d0 = dt * 64;
    int t = threadIdx.x;
    #pragma unroll
    for (int i = 0; i < 16; i++) {
        int idx = i * 256 + t;
        int n = idx >> 6, d = idx & 63;
        tile[n][d] = src[((size_t)(b * NN + n0 + n)) * DD + d0 + d];
    }
    __syncthreads();
    #pragma unroll
    for (int i = 0; i < 16; i++) {
        int idx = i * 256 + t;
        int d = idx >> 6, n = idx & 63;
        dst[((size_t)(b * DD + d0 + d)) * NN + n0 + n] = tile[n][d];
    }
}

// ---------------------------------------------------------------- k4: T[b,m,k,e] = sum_n A(g,wm)[m,n] * node[b,n,e]
//                     also accumulates neigh counts (atomicAdd into ncnt)
__global__ __launch_bounds__(256) void k4_stageA(const int* __restrict__ graphs,
        const float* __restrict__ wm, const __bf16* __restrict__ node_t,
        __bf16* __restrict__ T, int* __restrict__ ncnt) {
    __shared__ __align__(16) __bf16 Asub[64][72];
    __shared__ __align__(16) __bf16 Bsub[256][72];
    int bx = blockIdx.x;
    int mt = bx & 7;
    int kb = bx >> 3;
    int b = kb & 15;
    int k = kb >> 4;
    int m0 = mt * 64;
    int t = threadIdx.x;
    int lane = t & 63;
    int wave = t >> 6;                 // wave -> d block of 64
    int q = lane >> 4;
    int l16 = lane & 15;

    f32x4 acc[4][4];
    #pragma unroll
    for (int i = 0; i < 4; i++)
        #pragma unroll
        for (int j = 0; j < 4; j++) acc[i][j] = (f32x4){0.f, 0.f, 0.f, 0.f};

    int am = t >> 2;                   // A row 0..63
    int aq = t & 3;
    const int* grow = graphs + ((size_t)((k * BB + b) * NN + m0 + am)) * NN;
    int mg = m0 + am;                  // global row index (for diagonal)
    int bd = t >> 2;                   // B tile d row base
    int bq = t & 3;
    int cnt = 0;                       // unscaled neighbor count for row mg

    for (int n0 = 0; n0 < NN; n0 += 64) {
        // A tile: masked, w-scaled adjacency -> bf16 (+ neigh counting)
        #pragma unroll
        for (int i = 0; i < 4; i++) {
            int nbase = n0 + aq * 16 + i * 4;
            int4 g = *(const int4*)(grow + nbase);
            float4 w4 = *(const float4*)(wm + b * NN + nbase);
            bool v0ok = (nbase + 0 != mg) && (w4.x != 0.0f);
            bool v1ok = (nbase + 1 != mg) && (w4.y != 0.0f);
            bool v2ok = (nbase + 2 != mg) && (w4.z != 0.0f);
            bool v3ok = (nbase + 3 != mg) && (w4.w != 0.0f);
            cnt += (v0ok ? g.x : 0) + (v1ok ? g.y : 0) + (v2ok ? g.z : 0) + (v3ok ? g.w : 0);
            __bf16 v0 = (__bf16)(v0ok ? (float)g.x * w4.x : 0.0f);
            __bf16 v1 = (__bf16)(v1ok ? (float)g.y * w4.y : 0.0f);
            __bf16 v2 = (__bf16)(v2ok ? (float)g.z * w4.z : 0.0f);
            __bf16 v3 = (__bf16)(v3ok ? (float)g.w * w4.w : 0.0f);
            bf16x4 pack = {v0, v1, v2, v3};
            *(bf16x4*)&Asub[am][aq * 16 + i * 4] = pack;
        }
        // B tile: node_t[b][d][n0..n0+63]
        #pragma unroll
        for (int p = 0; p < 4; p++) {
            int d = bd + p * 64;
            const __bf16* src = node_t + ((size_t)(b * DD + d)) * NN + n0 + bq * 16;
            bf16x8 u0 = *(const bf16x8*)(src);
            bf16x8 u1 = *(const bf16x8*)(src + 8);
            *(bf16x8*)&Bsub[d][bq * 16]     = u0;
            *(bf16x8*)&Bsub[d][bq * 16 + 8] = u1;
        }
        __syncthreads();
        bf16x8 af[4][2], bfr[4][2];
        #pragma unroll
        for (int fm = 0; fm < 4; fm++)
            #pragma unroll
            for (int kk = 0; kk < 2; kk++)
                af[fm][kk] = *(const bf16x8*)&Asub[fm * 16 + l16][kk * 32 + q * 8];
        #pragma unroll
        for (int fd = 0; fd < 4; fd++)
            #pragma unroll
            for (int kk = 0; kk < 2; kk++)
                bfr[fd][kk] = *(const bf16x8*)&Bsub[wave * 64 + fd * 16 + l16][kk * 32 + q * 8];
        #pragma unroll
        for (int fm = 0; fm < 4; fm++)
            #pragma unroll
            for (int fd = 0; fd < 4; fd++)
                #pragma unroll
                for (int kk = 0; kk < 2; kk++)
                    acc[fm][fd] = __builtin_amdgcn_mfma_f32_16x16x32_bf16(
                        af[fm][kk], bfr[fd][kk], acc[fm][fd], 0, 0, 0);
        __syncthreads();
    }
    // neigh: reduce the 4 lanes that share row am, one atomic per row per block
    cnt += __shfl_xor(cnt, 1);
    cnt += __shfl_xor(cnt, 2);
    if ((t & 3) == 0) atomicAdd(&ncnt[b * NN + mg], cnt);

    // epilogue: store T bf16 in [b][m][k][e] layout. C/D: col=lane&15, row=(lane>>4)*4+reg
    #pragma unroll
    for (int fm = 0; fm < 4; fm++)
        #pragma unroll
        for (int fd = 0; fd < 4; fd++) {
            int col = wave * 64 + fd * 16 + l16;
            #pragma unroll
            for (int r = 0; r < 4; r++) {
                int m = m0 + fm * 16 + q * 4 + r;
                T[((size_t)((b * NN + m) * KK + k)) * DD + col] = (__bf16)acc[fm][fd][r];
            }
        }
}

// ---------------------------------------------------------------- k5: flat GEMM  out = relu(s*agg + self + bs)
// M=8192 (b*512+m), N=256 (d), Kred=3072 (k*256+e) + 256 self segment.
// Tile 64x128, 4 waves (2x2), BK=128 -> 24 main iters + 2 self iters.
__global__ __launch_bounds__(256) void k5_stageB(const __bf16* __restrict__ T,
        const __bf16* __restrict__ Wk_bf, const __bf16* __restrict__ node_bf,
        const __bf16* __restrict__ Ws_bf, const float* __restrict__ bs,
        const int* __restrict__ ncnt, const int* __restrict__ node_mask,
        float* __restrict__ out) {
    __shared__ __align__(16) __bf16 Asub[64][136];
    __shared__ __align__(16) __bf16 Bsub[128][136];
    int bx = blockIdx.x;
    int rt = bx & 127;                 // row tile 0..127
    int dt = bx >> 7;                  // col tile 0..1
    int b  = rt >> 3;
    int m0 = (rt & 7) * 64;
    int t = threadIdx.x;
    int lane = t & 63;
    int wave = t >> 6;
    int wm2 = wave >> 1;               // m half (32 rows)
    int wd2 = wave & 1;                // d half (64 cols)
    int q = lane >> 4;
    int l16 = lane & 15;

    f32x4 acc[2][4];
    #pragma unroll
    for (int i = 0; i < 2; i++)
        #pragma unroll
        for (int j = 0; j < 4; j++) acc[i][j] = (f32x4){0.f, 0.f, 0.f, 0.f};

    int ar = t >> 2; int ac = (t & 3) * 32;       // A: 64 rows x 128 cols
    int br = t >> 1; int bc = (t & 1) * 64;       // B: 128 rows x 128 cols

    const __bf16* Arow = T + (size_t)(b * NN + m0 + ar) * (KK * DD);
    const __bf16* Brow0 = Wk_bf + (size_t)(dt * 128 + br) * DD;   // + k*DD*DD

    for (int it = 0; it < 24; it++) {
        int kred0 = it * 128;
        int k = it >> 1;
        int e0 = (it & 1) * 128;
        const __bf16* asrc = Arow + kred0 + ac;
        #pragma unroll
        for (int i = 0; i < 4; i++)
            *(bf16x8*)&Asub[ar][ac + i * 8] = *(const bf16x8*)(asrc + i * 8);
        const __bf16* bsrc = Brow0 + (size_t)k * DD * DD + e0 + bc;
        #pragma unroll
        for (int i = 0; i < 8; i++)
            *(bf16x8*)&Bsub[br][bc + i * 8] = *(const bf16x8*)(bsrc + i * 8);
        __syncthreads();
        #pragma unroll
        for (int kk = 0; kk < 4; kk++) {
            bf16x8 af[2], bfr[4];
            #pragma unroll
            for (int fm = 0; fm < 2; fm++)
                af[fm] = *(const bf16x8*)&Asub[wm2 * 32 + fm * 16 + l16][kk * 32 + q * 8];
            #pragma unroll
            for (int fd = 0; fd < 4; fd++)
                bfr[fd] = *(const bf16x8*)&Bsub[wd2 * 64 + fd * 16 + l16][kk * 32 + q * 8];
            #pragma unroll
            for (int fm = 0; fm < 2; fm++)
                #pragma unroll
                for (int fd = 0; fd < 4; fd++)
                    acc[fm][fd] = __builtin_amdgcn_mfma_f32_16x16x32_bf16(
                        af[fm], bfr[fd], acc[fm][fd], 0, 0, 0);
        }
        __syncthreads();
    }

    // scale aggregate by s[b,m] = mask_m / max(1, cnt)
    #pragma unroll
    for (int fm = 0; fm < 2; fm++) {
        #pragma unroll
        for (int r = 0; r < 4; r++) {
            int m = m0 + wm2 * 32 + fm * 16 + q * 4 + r;
            int mk = node_mask[b * NN + m];
            int c  = ncnt[b * NN + m];
            float s = (float)mk / (float)(c >= 1 ? c : 1);
            #pragma unroll
            for (int fd = 0; fd < 4; fd++) acc[fm][fd][r] *= s;
        }
    }

    // self segments: + node @ Ws^T  (2 x BK=128)
    const __bf16* ArowS = node_bf + (size_t)(b * NN + m0 + ar) * DD;
    const __bf16* BrowS = Ws_bf + (size_t)(dt * 128 + br) * DD;
    for (int si = 0; si < 2; si++) {
        int e0 = si * 128;
        const __bf16* asrc = ArowS + e0 + ac;
        #pragma unroll
        for (int i = 0; i < 4; i++)
            *(bf16x8*)&Asub[ar][ac + i * 8] = *(const bf16x8*)(asrc + i * 8);
        const __bf16* bsrc = BrowS + e0 + bc;
        #pragma unroll
        for (int i = 0; i < 8; i++)
            *(bf16x8*)&Bsub[br][bc + i * 8] = *(const bf16x8*)(bsrc + i * 8);
        __syncthreads();
        #pragma unroll
        for (int kk = 0; kk < 4; kk++) {
            bf16x8 af[2], bfr[4];
            #pragma unroll
            for (int fm = 0; fm < 2; fm++)
                af[fm] = *(const bf16x8*)&Asub[wm2 * 32 + fm * 16 + l16][kk * 32 + q * 8];
            #pragma unroll
            for (int fd = 0; fd < 4; fd++)
                bfr[fd] = *(const bf16x8*)&Bsub[wd2 * 64 + fd * 16 + l16][kk * 32 + q * 8];
            #pragma unroll
            for (int fm = 0; fm < 2; fm++)
                #pragma unroll
                for (int fd = 0; fd < 4; fd++)
                    acc[fm][fd] = __builtin_amdgcn_mfma_f32_16x16x32_bf16(
                        af[fm], bfr[fd], acc[fm][fd], 0, 0, 0);
        }
        __syncthreads();
    }

    // epilogue: + bs, relu, store f32
    #pragma unroll
    for (int fm = 0; fm < 2; fm++)
        #pragma unroll
        for (int fd = 0; fd < 4; fd++) {
            int d = dt * 128 + wd2 * 64 + fd * 16 + l16;
            float bsv = bs[d];
            #pragma unroll
            for (int r = 0; r < 4; r++) {
                int m = m0 + wm2 * 32 + fm * 16 + q * 4 + r;
                float v = acc[fm][fd][r] + bsv;
                out[((size_t)(b * NN + m)) * DD + d] = fmaxf(v, 0.0f);
            }
        }
}

// ----------------------------------------------------------------
extern "C" void kernel_launch(void* const* d_in, const int* in_sizes, int n_in,
                              void* d_out, int out_size, void* d_ws, size_t ws_size,
                              hipStream_t stream) {
    const float* node      = (const float*)d_in[0];
    const float* Ww        = (const float*)d_in[1];
    const float* bw        = (const float*)d_in[2];
    const float* Ws        = (const float*)d_in[3];
    const float* bs        = (const float*)d_in[4];
    const float* Wk        = (const float*)d_in[5];
    const int*   node_mask = (const int*)d_in[6];
    const int*   graphs    = (const int*)d_in[7];
    float* out   = (float*)d_out;
    float* all_w = out + (size_t)BB * NN * DD;

    char* ws = (char*)d_ws;
    float*  wm      = (float*)(ws + WS_WM);
    int*    ncnt    = (int*)(ws + WS_NCNT);
    __bf16* node_bf = (__bf16*)(ws + WS_NODEBF);
    __bf16* node_t  = (__bf16*)(ws + WS_NODET);
    __bf16* Wk_bf   = (__bf16*)(ws + WS_WKBF);
    __bf16* Ws_bf   = (__bf16*)(ws + WS_WSBF);
    __bf16* Tbuf    = (__bf16*)(ws + WS_T);

    hipMemsetAsync(ncnt, 0, BB * NN * sizeof(int), stream);
    k1_prep    <<<2048, 256, 0, stream>>>(node, Ww, bw, node_mask, wm, node_bf, all_w);
    k1b_convert<<< 832, 256, 0, stream>>>(Wk, Ws, Wk_bf, Ws_bf);
    k2_transpose<<<512, 256, 0, stream>>>(node_bf, node_t);
    k4_stageA  <<<1536, 256, 0, stream>>>(graphs, wm, node_t, Tbuf, ncnt);
    k5_stageB  <<< 256, 256, 0, stream>>>(Tbuf, Wk_bf, node_bf, Ws_bf, bs, ncnt, node_mask, out);
}